// Round 6
// baseline (318.672 us; speedup 1.0000x reference)
//
#include <hip/hip_runtime.h>
#include <hip/hip_fp16.h>

#define HW 65536
#define PW 256        // plane width
#define C7S 168       // conv7 LDS row stride in halves (84 dw == 20 mod 32: bank-spread)
#define C5S 140       // conv5 LDS row stride in floats (140 dw == 12 mod 32: bank-spread)

__device__ __forceinline__ float gelu_f(float v) {
    return 0.5f * v * (1.0f + erff(v * 0.7071067811865476f));
}

__device__ __forceinline__ unsigned pack2h(float a, float b) {
    __half2 h = __floats2half2_rn(a, b);
    return *reinterpret_cast<unsigned*>(&h);
}

__device__ __forceinline__ void unpack8(uint4 u, float* dst) {
    float2 f;
    f = __half22float2(*reinterpret_cast<__half2*>(&u.x)); dst[0] = f.x; dst[1] = f.y;
    f = __half22float2(*reinterpret_cast<__half2*>(&u.y)); dst[2] = f.x; dst[3] = f.y;
    f = __half22float2(*reinterpret_cast<__half2*>(&u.z)); dst[4] = f.x; dst[5] = f.y;
    f = __half22float2(*reinterpret_cast<__half2*>(&u.w)); dst[6] = f.x; dst[7] = f.y;
}

__device__ __forceinline__ float sgpr_f(float v) {
    union { float f; int i; } u;
    u.f = v;
    u.i = __builtin_amdgcn_readfirstlane(u.i);
    return u.f;
}

// ---------------- K0: pool x over H,W (partial sums, 4 blocks per plane) ------
__global__ __launch_bounds__(256) void k_pool_x(const float* __restrict__ x,
                                                float* __restrict__ partial) {
    __shared__ float red[256];
    const int t = threadIdx.x;
    const int blk = blockIdx.x;              // plane*4 + quarter
    const float* p = x + (size_t)blk * 16384;
    float s = 0.f;
    #pragma unroll
    for (int i = 0; i < 16; ++i) {
        float4 v = *reinterpret_cast<const float4*>(p + (i * 256 + t) * 4);
        s += v.x + v.y + v.z + v.w;
    }
    red[t] = s;
    __syncthreads();
    for (int off = 128; off > 0; off >>= 1) {
        if (t < off) red[t] += red[t + off];
        __syncthreads();
    }
    if (t == 0) partial[blk] = red[0];
}

// ------------- K1/K3: reduce partials -> routing -> mixed kernels -------------
__global__ __launch_bounds__(64) void k_route_mix(const float* __restrict__ partial,
                                                  const float* __restrict__ rw,
                                                  const float* __restrict__ rb,
                                                  const float* __restrict__ wexp,
                                                  float* __restrict__ wkout,
                                                  int taps, int parts) {
    __shared__ float pool_s[64];
    __shared__ float r_s[3];
    const int b = blockIdx.x, c = threadIdx.x;   // 64 threads = channels
    float s = 0.f;
    for (int q = 0; q < parts; ++q) s += partial[(b * 64 + c) * parts + q];
    pool_s[c] = s * (1.0f / 65536.0f);
    __syncthreads();
    if (c < 3) {
        float z = rb[c];
        #pragma unroll
        for (int i = 0; i < 64; ++i) z += pool_s[i] * rw[c * 64 + i];
        r_s[c] = 1.0f / (1.0f + expf(-z));
    }
    __syncthreads();
    const float r0 = r_s[0], r1 = r_s[1], r2 = r_s[2];
    for (int j = 0; j < taps; ++j) {
        wkout[(b * 64 + c) * taps + j] =
            r0 * wexp[(0 * 64 + c) * taps + j] +
            r1 * wexp[(1 * 64 + c) * taps + j] +
            r2 * wexp[(2 * 64 + c) * taps + j];
    }
}

// -------- K2: depthwise 5x5 pad2 + bias + gelu -> fp16, with tile sums --------
// Same structure as the working conv7: 64x128 output tile, f32 LDS stage
// (68 rows x 140-stride, halo zero-filled), 1 row x 32 cols per thread,
// weights in SGPRs, static dy-loop (5 bodies x 10 ds_read_b128 + 160 FMA).
__global__ __launch_bounds__(256) void k_conv5(const float* __restrict__ x,
                                               const float* __restrict__ wk,
                                               const float* __restrict__ bias,
                                               __half* __restrict__ attn0,
                                               float* __restrict__ tilesum) {
    __shared__ float lds[68 * C5S];          // 38080 B
    __shared__ float red[256];
    const int blk = blockIdx.x;              // plane*8 + tile (64-row x 128-col)
    const int plane = blk >> 3;
    const int tile = blk & 7;
    const int c = plane & 63;
    const int oy0 = (tile >> 1) << 6;        // 0,64,128,192
    const int ox0 = (tile & 1) << 7;         // 0,128
    const int t = threadIdx.x;
    const float* xp = x + (size_t)plane * HW;

    // stage rows gy = oy0-2+lr (lr 0..67), cols gx = ox0-4+4*c4 (c4 0..33)
    #pragma unroll
    for (int it = 0; it < 10; ++it) {
        const int idx = it * 256 + t;
        if (idx < 2312) {                    // 68*34
            const int lr = idx / 34;
            const int c4 = idx - lr * 34;
            const int gy = oy0 - 2 + lr;
            const int gx = ox0 - 4 + (c4 << 2);
            float4 v = make_float4(0.f, 0.f, 0.f, 0.f);
            if ((unsigned)gy < 256u && (unsigned)gx < 256u)
                v = *reinterpret_cast<const float4*>(xp + gy * PW + gx);
            *reinterpret_cast<float4*>(&lds[lr * C5S + (c4 << 2)]) = v;
        }
    }

    // weights -> SGPRs (block-uniform)
    float w[25];
    #pragma unroll
    for (int i = 0; i < 25; ++i) w[i] = sgpr_f(wk[plane * 25 + i]);
    __syncthreads();

    const int tx = t & 3, ty = t >> 2;       // 4 x 64
    const int ox = tx << 5;                  // tile-local col base: 0,32,64,96
    float acc[32];
    #pragma unroll
    for (int j = 0; j < 32; ++j) acc[j] = 0.f;

    #pragma unroll
    for (int dy = 0; dy < 5; ++dy) {
        const int lr = ty + dy;              // 0..67
        const float* lp = &lds[lr * C5S + ox];
        float buf[40];                       // local cols ox..ox+39; used +2..+37
        #pragma unroll
        for (int k = 0; k < 10; ++k) {
            float4 v = *reinterpret_cast<const float4*>(lp + (k << 2));
            buf[k * 4 + 0] = v.x; buf[k * 4 + 1] = v.y;
            buf[k * 4 + 2] = v.z; buf[k * 4 + 3] = v.w;
        }
        #pragma unroll
        for (int dx = 0; dx < 5; ++dx) {
            const float wv = w[dy * 5 + dx];
            #pragma unroll
            for (int j = 0; j < 32; ++j)
                acc[j] += wv * buf[j + dx + 2];
        }
    }

    const float bs = bias[c];
    float lsum = 0.f;
    __half* op = attn0 + (size_t)plane * HW + (size_t)(oy0 + ty) * PW + ox0 + ox;
    #pragma unroll
    for (int q = 0; q < 4; ++q) {
        float g[8];
        #pragma unroll
        for (int j = 0; j < 8; ++j) {
            g[j] = gelu_f(acc[q * 8 + j] + bs);
            lsum += g[j];
        }
        uint4 st;
        st.x = pack2h(g[0], g[1]); st.y = pack2h(g[2], g[3]);
        st.z = pack2h(g[4], g[5]); st.w = pack2h(g[6], g[7]);
        *reinterpret_cast<uint4*>(op + (q << 3)) = st;
    }
    red[t] = lsum;
    __syncthreads();
    for (int off = 128; off > 0; off >>= 1) {
        if (t < off) red[t] += red[t + off];
        __syncthreads();
    }
    if (t == 0) tilesum[blk] = red[0];
}

// -------- K4: depthwise 7x7 dil3 pad9 + bias + gelu, fp16 -> fp16 -------------
// (unchanged from round 5: 104 us, VGPR=128, no spill, VALUBusy 66%)
__global__ __launch_bounds__(256) void k_conv7(const __half* __restrict__ a0,
                                               const float* __restrict__ wk,
                                               const float* __restrict__ bias,
                                               __half* __restrict__ attn1) {
    __shared__ __half lds[82 * C7S];         // 27552 B
    const int blk = blockIdx.x;              // plane*8 + tile (64-row x 128-col)
    const int plane = blk >> 3;
    const int tile = blk & 7;
    const int c = plane & 63;
    const int oy0 = (tile >> 1) << 6;        // 0,64,128,192
    const int ox0 = (tile & 1) << 7;         // 0,128
    const int t = threadIdx.x;
    const __half* ap = a0 + (size_t)plane * HW;

    const uint4 z4 = make_uint4(0u, 0u, 0u, 0u);
    #pragma unroll
    for (int it = 0; it < 7; ++it) {
        const int idx = it * 256 + t;
        if (idx < 1722) {                    // 82*21
            const int lr = idx / 21;
            const int c8 = idx - lr * 21;
            const int gy = oy0 - 9 + lr;
            const int gx = ox0 - 16 + (c8 << 3);
            uint4 v = z4;
            if ((unsigned)gy < 256u && (unsigned)gx < 256u)
                v = *reinterpret_cast<const uint4*>(ap + gy * PW + gx);
            *reinterpret_cast<uint4*>(&lds[lr * C7S + (c8 << 3)]) = v;
        }
    }

    float w[49];
    #pragma unroll
    for (int i = 0; i < 49; ++i) w[i] = sgpr_f(wk[plane * 49 + i]);
    __syncthreads();

    const int tx = t & 3, ty = t >> 2;       // 4 x 64
    const int ox = tx << 5;                  // 32-wide strip: 0,32,64,96
    float acc[32];
    #pragma unroll
    for (int j = 0; j < 32; ++j) acc[j] = 0.f;

    #pragma unroll
    for (int dyi = 0; dyi < 7; ++dyi) {
        const int lr = ty + 3 * dyi;         // 0..81
        const __half* lp = &lds[lr * C7S + ox];
        float buf[64];                       // lds cols ox..ox+63; used 7..56
        #pragma unroll
        for (int k = 0; k < 8; ++k) {
            uint4 u = *reinterpret_cast<const uint4*>(lp + (k << 3));
            unpack8(u, buf + (k << 3));
        }
        #pragma unroll
        for (int dxi = 0; dxi < 7; ++dxi) {
            const float wv = w[dyi * 7 + dxi];
            #pragma unroll
            for (int j = 0; j < 32; ++j)
                acc[j] += wv * buf[7 + j + 3 * dxi];
        }
    }

    const float bs = bias[c];
    __half* op = attn1 + (size_t)plane * HW + (size_t)(oy0 + ty) * PW + ox0 + ox;
    #pragma unroll
    for (int q = 0; q < 4; ++q) {
        float g[8];
        #pragma unroll
        for (int j = 0; j < 8; ++j) g[j] = gelu_f(acc[q * 8 + j] + bs);
        uint4 st;
        st.x = pack2h(g[0], g[1]); st.y = pack2h(g[2], g[3]);
        st.z = pack2h(g[4], g[5]); st.w = pack2h(g[6], g[7]);
        *reinterpret_cast<uint4*>(op + (q << 3)) = st;
    }
}

// -------- K5: 1x1 channel mix + bias, then out = x * attn ---------------------
__global__ __launch_bounds__(256) void k_mix(const __half* __restrict__ attn1,
                                             const float* __restrict__ wpm,
                                             const float* __restrict__ bp,
                                             const float* __restrict__ x,
                                             float* __restrict__ out) {
    __shared__ __half A_s[64][256];
    __shared__ float wpT[64][64];
    const int t = threadIdx.x;
    const int blk = blockIdx.x;
    const int b = blk >> 8;
    const int p0g = (blk & 255) << 8;        // 256-pixel chunk
    #pragma unroll
    for (int it = 0; it < 8; ++it) {
        const int ci = it * 256 + t;
        const int row = ci >> 5;
        const int off = (ci & 31) << 3;
        uint4 u = *reinterpret_cast<const uint4*>(attn1 + (size_t)(b * 64 + row) * HW + p0g + off);
        *reinterpret_cast<uint4*>(&A_s[row][off]) = u;
    }
    #pragma unroll
    for (int j = 0; j < 16; ++j) {
        const int idx = j * 256 + t;
        const int cc = idx & 63;
        const int oo = idx >> 6;
        wpT[cc][oo] = wpm[oo * 64 + cc];     // coalesced read, conflicted write (once)
    }
    __syncthreads();
    const int o0 = (t >> 5) << 3;
    const int p0 = (t & 31) << 3;
    float acc[8][8];
    #pragma unroll
    for (int i = 0; i < 8; ++i)
        #pragma unroll
        for (int j = 0; j < 8; ++j) acc[i][j] = 0.f;
    #pragma unroll 4
    for (int cc = 0; cc < 64; ++cc) {
        float4 wa = *reinterpret_cast<const float4*>(&wpT[cc][o0]);
        float4 wb = *reinterpret_cast<const float4*>(&wpT[cc][o0 + 4]);
        const float wv[8] = {wa.x, wa.y, wa.z, wa.w, wb.x, wb.y, wb.z, wb.w};
        float af[8];
        uint4 u = *reinterpret_cast<const uint4*>(&A_s[cc][p0]);
        unpack8(u, af);
        #pragma unroll
        for (int oo = 0; oo < 8; ++oo) {
            const float wvv = wv[oo];
            #pragma unroll
            for (int pp = 0; pp < 8; ++pp) acc[oo][pp] += wvv * af[pp];
        }
    }
    #pragma unroll
    for (int oo = 0; oo < 8; ++oo) {
        const int o = o0 + oo;
        const float bb = bp[o];
        const size_t base = (size_t)(b * 64 + o) * HW + p0g + p0;
        float4 x0 = *reinterpret_cast<const float4*>(x + base);
        float4 x1 = *reinterpret_cast<const float4*>(x + base + 4);
        float4 r0, r1;
        r0.x = x0.x * (acc[oo][0] + bb); r0.y = x0.y * (acc[oo][1] + bb);
        r0.z = x0.z * (acc[oo][2] + bb); r0.w = x0.w * (acc[oo][3] + bb);
        r1.x = x1.x * (acc[oo][4] + bb); r1.y = x1.y * (acc[oo][5] + bb);
        r1.z = x1.z * (acc[oo][6] + bb); r1.w = x1.w * (acc[oo][7] + bb);
        *reinterpret_cast<float4*>(out + base) = r0;
        *reinterpret_cast<float4*>(out + base + 4) = r1;
    }
}

extern "C" void kernel_launch(void* const* d_in, const int* in_sizes, int n_in,
                              void* d_out, int out_size, void* d_ws, size_t ws_size,
                              hipStream_t stream) {
    const float* x   = (const float*)d_in[0];
    const float* w0  = (const float*)d_in[1];
    const float* b0  = (const float*)d_in[2];
    const float* r0w = (const float*)d_in[3];
    const float* r0b = (const float*)d_in[4];
    const float* w1  = (const float*)d_in[5];
    const float* b1  = (const float*)d_in[6];
    const float* r1w = (const float*)d_in[7];
    const float* r1b = (const float*)d_in[8];
    const float* wpm = (const float*)d_in[9];
    const float* bp  = (const float*)d_in[10];
    float* out = (float*)d_out;

    // workspace layout (needs ~134.5 MB)
    char* ws = (char*)d_ws;
    __half* attn0   = (__half*)(ws);                       // 64 MB
    __half* attn1   = (__half*)(ws + 67108864);            // 64 MB
    float* partial0 = (float*)(ws + 134217728);            // 2048 f32
    float* tilesum1 = (float*)(ws + 134217728 + 16384);    // 4096 f32
    float* wk0      = (float*)(ws + 134217728 + 65536);    // 512*25 f32
    float* wk1      = (float*)(ws + 134217728 + 65536 + 51200); // 512*49 f32

    k_pool_x<<<2048, 256, 0, stream>>>(x, partial0);
    k_route_mix<<<8, 64, 0, stream>>>(partial0, r0w, r0b, w0, wk0, 25, 4);
    k_conv5<<<4096, 256, 0, stream>>>(x, wk0, b0, attn0, tilesum1);
    k_route_mix<<<8, 64, 0, stream>>>(tilesum1, r1w, r1b, w1, wk1, 49, 8);
    k_conv7<<<4096, 256, 0, stream>>>(attn0, wk1, b1, attn1);
    k_mix<<<2048, 256, 0, stream>>>(attn1, wpm, bp, x, out);
}

// Round 7
// 266.134 us; speedup vs baseline: 1.1974x; 1.1974x over previous
//
#include <hip/hip_runtime.h>
#include <hip/hip_fp16.h>

#define HW 65536
#define PW 256        // plane width
#define C7S 168       // conv7 LDS row stride in halves (84 dw == 20 mod 32: bank-spread)

// Fast exact-gelu: erf via Abramowitz-Stegun 7.1.26 (|err| <= 1.5e-7).
// libm erff was ~50 instr and dominated both conv kernels' VALU (R6 post-mortem).
__device__ __forceinline__ float gelu_f(float v) {
    float ax = fabsf(v) * 0.7071067811865476f;
    float t  = 1.0f / (1.0f + 0.3275911f * ax);
    float p  = t * (0.254829592f + t * (-0.284496736f + t * (1.421413741f
             + t * (-1.453152027f + t * 1.061405429f))));
    float e  = 1.0f - p * __expf(-ax * ax);
    e = copysignf(e, v);
    return 0.5f * v * (1.0f + e);
}

__device__ __forceinline__ unsigned pack2h(float a, float b) {
    __half2 h = __floats2half2_rn(a, b);
    return *reinterpret_cast<unsigned*>(&h);
}

__device__ __forceinline__ void unpack8(uint4 u, float* dst) {
    float2 f;
    f = __half22float2(*reinterpret_cast<__half2*>(&u.x)); dst[0] = f.x; dst[1] = f.y;
    f = __half22float2(*reinterpret_cast<__half2*>(&u.y)); dst[2] = f.x; dst[3] = f.y;
    f = __half22float2(*reinterpret_cast<__half2*>(&u.z)); dst[4] = f.x; dst[5] = f.y;
    f = __half22float2(*reinterpret_cast<__half2*>(&u.w)); dst[6] = f.x; dst[7] = f.y;
}

__device__ __forceinline__ float sgpr_f(float v) {
    union { float f; int i; } u;
    u.f = v;
    u.i = __builtin_amdgcn_readfirstlane(u.i);
    return u.f;
}

// ---------------- K0: pool x over H,W (partial sums, 4 blocks per plane) ------
__global__ __launch_bounds__(256) void k_pool_x(const float* __restrict__ x,
                                                float* __restrict__ partial) {
    __shared__ float red[256];
    const int t = threadIdx.x;
    const int blk = blockIdx.x;              // plane*4 + quarter
    const float* p = x + (size_t)blk * 16384;
    float s = 0.f;
    #pragma unroll
    for (int i = 0; i < 16; ++i) {
        float4 v = *reinterpret_cast<const float4*>(p + (i * 256 + t) * 4);
        s += v.x + v.y + v.z + v.w;
    }
    red[t] = s;
    __syncthreads();
    for (int off = 128; off > 0; off >>= 1) {
        if (t < off) red[t] += red[t + off];
        __syncthreads();
    }
    if (t == 0) partial[blk] = red[0];
}

// ------------- K1/K3: reduce partials -> routing -> mixed kernels -------------
__global__ __launch_bounds__(64) void k_route_mix(const float* __restrict__ partial,
                                                  const float* __restrict__ rw,
                                                  const float* __restrict__ rb,
                                                  const float* __restrict__ wexp,
                                                  float* __restrict__ wkout,
                                                  int taps, int parts) {
    __shared__ float pool_s[64];
    __shared__ float r_s[3];
    const int b = blockIdx.x, c = threadIdx.x;   // 64 threads = channels
    float s = 0.f;
    for (int q = 0; q < parts; ++q) s += partial[(b * 64 + c) * parts + q];
    pool_s[c] = s * (1.0f / 65536.0f);
    __syncthreads();
    if (c < 3) {
        float z = rb[c];
        #pragma unroll
        for (int i = 0; i < 64; ++i) z += pool_s[i] * rw[c * 64 + i];
        r_s[c] = 1.0f / (1.0f + expf(-z));
    }
    __syncthreads();
    const float r0 = r_s[0], r1 = r_s[1], r2 = r_s[2];
    for (int j = 0; j < taps; ++j) {
        wkout[(b * 64 + c) * taps + j] =
            r0 * wexp[(0 * 64 + c) * taps + j] +
            r1 * wexp[(1 * 64 + c) * taps + j] +
            r2 * wexp[(2 * 64 + c) * taps + j];
    }
}

// -------- K2: depthwise 5x5 pad2 + bias + gelu -> fp16, with tile sums --------
// R5 structure (global float4 loads, 8x8/thread — 58 us): LDS port regressed
// it to 105 us (R6), reverted. Only change: fast gelu.
__global__ __launch_bounds__(256) void k_conv5(const float* __restrict__ x,
                                               const float* __restrict__ wk,
                                               const float* __restrict__ bias,
                                               __half* __restrict__ attn0,
                                               float* __restrict__ tilesum) {
    __shared__ float red[256];
    const int blk = blockIdx.x;              // plane*4 + tile (128x128 tiles)
    const int plane = blk >> 2;
    const int tile = blk & 3;
    const int c = plane & 63;
    const int oy0 = (tile >> 1) << 7;
    const int ox0 = (tile & 1) << 7;
    const int t = threadIdx.x;
    const int ox = ox0 + ((t & 15) << 3);    // 8-wide strip
    const int oy = oy0 + ((t >> 4) << 3);    // 8-tall
    const float* xp = x + (size_t)plane * HW;
    const float* wkp = wk + plane * 25;
    float w[25];
    #pragma unroll
    for (int i = 0; i < 25; ++i) w[i] = sgpr_f(wkp[i]);
    float acc[8][8];
    #pragma unroll
    for (int i = 0; i < 8; ++i)
        #pragma unroll
        for (int j = 0; j < 8; ++j) acc[i][j] = 0.f;

    #pragma unroll
    for (int r = 0; r < 12; ++r) {
        const int gy = oy - 2 + r;
        if (gy >= 0 && gy < 256) {
            const float* rp = xp + gy * PW + ox;
            float buf[16];
            float4 v;
            if (ox > 0) v = *reinterpret_cast<const float4*>(rp - 4);
            else        v = make_float4(0.f, 0.f, 0.f, 0.f);
            buf[0] = v.x; buf[1] = v.y; buf[2] = v.z; buf[3] = v.w;
            v = *reinterpret_cast<const float4*>(rp);
            buf[4] = v.x; buf[5] = v.y; buf[6] = v.z; buf[7] = v.w;
            v = *reinterpret_cast<const float4*>(rp + 4);
            buf[8] = v.x; buf[9] = v.y; buf[10] = v.z; buf[11] = v.w;
            if (ox < 248) v = *reinterpret_cast<const float4*>(rp + 8);
            else          v = make_float4(0.f, 0.f, 0.f, 0.f);
            buf[12] = v.x; buf[13] = v.y; buf[14] = v.z; buf[15] = v.w;
            #pragma unroll
            for (int i = 0; i < 8; ++i) {
                const int d = r - i;
                if (d >= 0 && d <= 4) {
                    #pragma unroll
                    for (int dx = 0; dx < 5; ++dx) {
                        const float wv = w[d * 5 + dx];
                        #pragma unroll
                        for (int j = 0; j < 8; ++j)
                            acc[i][j] += wv * buf[j + dx + 2];
                    }
                }
            }
        }
    }
    const float bs = bias[c];
    float lsum = 0.f;
    __half* op = attn0 + (size_t)plane * HW;
    #pragma unroll
    for (int i = 0; i < 8; ++i) {
        float g[8];
        #pragma unroll
        for (int j = 0; j < 8; ++j) {
            g[j] = gelu_f(acc[i][j] + bs);
            lsum += g[j];
        }
        uint4 st;
        st.x = pack2h(g[0], g[1]); st.y = pack2h(g[2], g[3]);
        st.z = pack2h(g[4], g[5]); st.w = pack2h(g[6], g[7]);
        *reinterpret_cast<uint4*>(op + (oy + i) * PW + ox) = st;
    }
    red[t] = lsum;
    __syncthreads();
    for (int off = 128; off > 0; off >>= 1) {
        if (t < off) red[t] += red[t + off];
        __syncthreads();
    }
    if (t == 0) tilesum[blk] = red[0];
}

// -------- K4: depthwise 7x7 dil3 pad9 + bias + gelu, fp16 -> fp16 -------------
// (R5 structure: 104 us, VGPR=128, no spill; only change: fast gelu)
__global__ __launch_bounds__(256) void k_conv7(const __half* __restrict__ a0,
                                               const float* __restrict__ wk,
                                               const float* __restrict__ bias,
                                               __half* __restrict__ attn1) {
    __shared__ __half lds[82 * C7S];         // 27552 B
    const int blk = blockIdx.x;              // plane*8 + tile (64-row x 128-col)
    const int plane = blk >> 3;
    const int tile = blk & 7;
    const int c = plane & 63;
    const int oy0 = (tile >> 1) << 6;        // 0,64,128,192
    const int ox0 = (tile & 1) << 7;         // 0,128
    const int t = threadIdx.x;
    const __half* ap = a0 + (size_t)plane * HW;

    const uint4 z4 = make_uint4(0u, 0u, 0u, 0u);
    #pragma unroll
    for (int it = 0; it < 7; ++it) {
        const int idx = it * 256 + t;
        if (idx < 1722) {                    // 82*21
            const int lr = idx / 21;
            const int c8 = idx - lr * 21;
            const int gy = oy0 - 9 + lr;
            const int gx = ox0 - 16 + (c8 << 3);
            uint4 v = z4;
            if ((unsigned)gy < 256u && (unsigned)gx < 256u)
                v = *reinterpret_cast<const uint4*>(ap + gy * PW + gx);
            *reinterpret_cast<uint4*>(&lds[lr * C7S + (c8 << 3)]) = v;
        }
    }

    float w[49];
    #pragma unroll
    for (int i = 0; i < 49; ++i) w[i] = sgpr_f(wk[plane * 49 + i]);
    __syncthreads();

    const int tx = t & 3, ty = t >> 2;       // 4 x 64
    const int ox = tx << 5;                  // 32-wide strip: 0,32,64,96
    float acc[32];
    #pragma unroll
    for (int j = 0; j < 32; ++j) acc[j] = 0.f;

    #pragma unroll
    for (int dyi = 0; dyi < 7; ++dyi) {
        const int lr = ty + 3 * dyi;         // 0..81
        const __half* lp = &lds[lr * C7S + ox];
        float buf[64];                       // lds cols ox..ox+63; used 7..56
        #pragma unroll
        for (int k = 0; k < 8; ++k) {
            uint4 u = *reinterpret_cast<const uint4*>(lp + (k << 3));
            unpack8(u, buf + (k << 3));
        }
        #pragma unroll
        for (int dxi = 0; dxi < 7; ++dxi) {
            const float wv = w[dyi * 7 + dxi];
            #pragma unroll
            for (int j = 0; j < 32; ++j)
                acc[j] += wv * buf[7 + j + 3 * dxi];
        }
    }

    const float bs = bias[c];
    __half* op = attn1 + (size_t)plane * HW + (size_t)(oy0 + ty) * PW + ox0 + ox;
    #pragma unroll
    for (int q = 0; q < 4; ++q) {
        float g[8];
        #pragma unroll
        for (int j = 0; j < 8; ++j) g[j] = gelu_f(acc[q * 8 + j] + bs);
        uint4 st;
        st.x = pack2h(g[0], g[1]); st.y = pack2h(g[2], g[3]);
        st.z = pack2h(g[4], g[5]); st.w = pack2h(g[6], g[7]);
        *reinterpret_cast<uint4*>(op + (q << 3)) = st;
    }
}

// -------- K5: 1x1 channel mix + bias, then out = x * attn ---------------------
__global__ __launch_bounds__(256) void k_mix(const __half* __restrict__ attn1,
                                             const float* __restrict__ wpm,
                                             const float* __restrict__ bp,
                                             const float* __restrict__ x,
                                             float* __restrict__ out) {
    __shared__ __half A_s[64][256];
    __shared__ float wpT[64][64];
    const int t = threadIdx.x;
    const int blk = blockIdx.x;
    const int b = blk >> 8;
    const int p0g = (blk & 255) << 8;        // 256-pixel chunk
    #pragma unroll
    for (int it = 0; it < 8; ++it) {
        const int ci = it * 256 + t;
        const int row = ci >> 5;
        const int off = (ci & 31) << 3;
        uint4 u = *reinterpret_cast<const uint4*>(attn1 + (size_t)(b * 64 + row) * HW + p0g + off);
        *reinterpret_cast<uint4*>(&A_s[row][off]) = u;
    }
    #pragma unroll
    for (int j = 0; j < 16; ++j) {
        const int idx = j * 256 + t;
        const int cc = idx & 63;
        const int oo = idx >> 6;
        wpT[cc][oo] = wpm[oo * 64 + cc];     // coalesced read, conflicted write (once)
    }
    __syncthreads();
    const int o0 = (t >> 5) << 3;
    const int p0 = (t & 31) << 3;
    float acc[8][8];
    #pragma unroll
    for (int i = 0; i < 8; ++i)
        #pragma unroll
        for (int j = 0; j < 8; ++j) acc[i][j] = 0.f;
    #pragma unroll 4
    for (int cc = 0; cc < 64; ++cc) {
        float4 wa = *reinterpret_cast<const float4*>(&wpT[cc][o0]);
        float4 wb = *reinterpret_cast<const float4*>(&wpT[cc][o0 + 4]);
        const float wv[8] = {wa.x, wa.y, wa.z, wa.w, wb.x, wb.y, wb.z, wb.w};
        float af[8];
        uint4 u = *reinterpret_cast<const uint4*>(&A_s[cc][p0]);
        unpack8(u, af);
        #pragma unroll
        for (int oo = 0; oo < 8; ++oo) {
            const float wvv = wv[oo];
            #pragma unroll
            for (int pp = 0; pp < 8; ++pp) acc[oo][pp] += wvv * af[pp];
        }
    }
    #pragma unroll
    for (int oo = 0; oo < 8; ++oo) {
        const int o = o0 + oo;
        const float bb = bp[o];
        const size_t base = (size_t)(b * 64 + o) * HW + p0g + p0;
        float4 x0 = *reinterpret_cast<const float4*>(x + base);
        float4 x1 = *reinterpret_cast<const float4*>(x + base + 4);
        float4 r0, r1;
        r0.x = x0.x * (acc[oo][0] + bb); r0.y = x0.y * (acc[oo][1] + bb);
        r0.z = x0.z * (acc[oo][2] + bb); r0.w = x0.w * (acc[oo][3] + bb);
        r1.x = x1.x * (acc[oo][4] + bb); r1.y = x1.y * (acc[oo][5] + bb);
        r1.z = x1.z * (acc[oo][6] + bb); r1.w = x1.w * (acc[oo][7] + bb);
        *reinterpret_cast<float4*>(out + base) = r0;
        *reinterpret_cast<float4*>(out + base + 4) = r1;
    }
}

extern "C" void kernel_launch(void* const* d_in, const int* in_sizes, int n_in,
                              void* d_out, int out_size, void* d_ws, size_t ws_size,
                              hipStream_t stream) {
    const float* x   = (const float*)d_in[0];
    const float* w0  = (const float*)d_in[1];
    const float* b0  = (const float*)d_in[2];
    const float* r0w = (const float*)d_in[3];
    const float* r0b = (const float*)d_in[4];
    const float* w1  = (const float*)d_in[5];
    const float* b1  = (const float*)d_in[6];
    const float* r1w = (const float*)d_in[7];
    const float* r1b = (const float*)d_in[8];
    const float* wpm = (const float*)d_in[9];
    const float* bp  = (const float*)d_in[10];
    float* out = (float*)d_out;

    // workspace layout (needs ~134.4 MB)
    char* ws = (char*)d_ws;
    __half* attn0   = (__half*)(ws);                       // 64 MB
    __half* attn1   = (__half*)(ws + 67108864);            // 64 MB
    float* partial0 = (float*)(ws + 134217728);            // 2048 f32
    float* tilesum1 = (float*)(ws + 134217728 + 8192);     // 2048 f32
    float* wk0      = (float*)(ws + 134217728 + 16384);    // 512*25 f32
    float* wk1      = (float*)(ws + 134217728 + 16384 + 51200); // 512*49 f32

    k_pool_x<<<2048, 256, 0, stream>>>(x, partial0);
    k_route_mix<<<8, 64, 0, stream>>>(partial0, r0w, r0b, w0, wk0, 25, 4);
    k_conv5<<<2048, 256, 0, stream>>>(x, wk0, b0, attn0, tilesum1);
    k_route_mix<<<8, 64, 0, stream>>>(tilesum1, r1w, r1b, w1, wk1, 49, 4);
    k_conv7<<<4096, 256, 0, stream>>>(attn0, wk1, b1, attn1);
    k_mix<<<2048, 256, 0, stream>>>(attn1, wpm, bp, x, out);
}